// Round 12
// baseline (2704.302 us; speedup 1.0000x reference)
//
#include <hip/hip_runtime.h>
#include <hip/hip_bf16.h>
#include <math.h>

typedef __hip_bfloat16 bf16;

#define B_ 32
#define HW_ 784
#define T_ 785
#define TP_ 197
#define C_ 384
#define H_ 8
#define D_ 48
#define FF_ 1536
#define CH_ 64    // (b,h) pairs per attention chunk
#define SP_ 788   // padded S row stride (floats, mult of 4 -> aligned float4)

// ---------------- sizes (elements) ----------------
static constexpr size_t NRES = (size_t)B_ * T_ * C_;
static constexpr size_t NX   = (size_t)B_ * HW_ * C_;
static constexpr size_t NCLS = (size_t)B_ * C_;
static constexpr size_t NLN1 = (size_t)T_ * C_;
static constexpr size_t NWP  = (size_t)C_ * C_;
static constexpr size_t NLN2 = (size_t)TP_ * C_;
static constexpr size_t NW1  = (size_t)FF_ * C_;
static constexpr size_t NX2  = (size_t)B_ * TP_ * C_;
static constexpr size_t NH   = (size_t)B_ * TP_ * FF_;

// ---------------- arena byte offsets ----------------
static constexpr size_t XF_OFF   = 0;
static constexpr size_t CLSF_OFF = XF_OFF   + NX   * 4;
static constexpr size_t LN1W_OFF = CLSF_OFF + NCLS * 4;
static constexpr size_t LN1B_OFF = LN1W_OFF + NLN1 * 4;
static constexpr size_t WQF_OFF  = LN1B_OFF + NLN1 * 4;
static constexpr size_t WKF_OFF  = WQF_OFF  + NWP  * 4;
static constexpr size_t WVF_OFF  = WKF_OFF  + NWP  * 4;
static constexpr size_t WOF_OFF  = WVF_OFF  + NWP  * 4;
static constexpr size_t LN2W_OFF = WOF_OFF  + NWP  * 4;
static constexpr size_t LN2B_OFF = LN2W_OFF + NLN2 * 4;
static constexpr size_t W1F_OFF  = LN2B_OFF + NLN2 * 4;
static constexpr size_t W2F_OFF  = W1F_OFF  + NW1  * 4;
static constexpr size_t X1_OFF   = W2F_OFF  + NW1  * 4;
static constexpr size_t Q_OFF    = X1_OFF   + NRES * 4;
static constexpr size_t K_OFF    = Q_OFF    + NRES * 4;
static constexpr size_t V_OFF    = K_OFF    + NRES * 4;
static constexpr size_t ATT_OFF  = V_OFF    + NRES * 4;
static constexpr size_t XM_OFF   = ATT_OFF  + NRES * 4;
static constexpr size_t RES_OFF  = XM_OFF   + NRES * 4;
static constexpr size_t X2N_OFF  = RES_OFF  + NRES * 4;
static constexpr size_t H_OFF    = X2N_OFF  + NX2  * 4;
static constexpr size_t MU_OFF   = H_OFF    + NH   * 4;
static constexpr size_t RS_OFF   = MU_OFF   + 128;
static constexpr size_t CID_OFF  = RS_OFF   + 128;
static constexpr size_t CAD_OFF  = CID_OFF  + NCLS * 8;
static constexpr size_t PERM_OFF = CAD_OFF  + (size_t)B_ * HW_ * 8;
static constexpr size_t FLAG_OFF = PERM_OFF + (size_t)B_ * (TP_ - 1) * 4;
static constexpr size_t PS_OFF   = FLAG_OFF + 16;
static constexpr size_t CIP_OFF  = PS_OFF + 32 * 16 * 16;
static constexpr size_t L2PS_OFF = CIP_OFF + (size_t)B_ * 8 * C_ * 8;
static constexpr size_t L2MU_OFF = L2PS_OFF + 32 * 8 * 16;
static constexpr size_t L2RS_OFF = L2MU_OFF + 128;
static constexpr size_t S_OFF    = L2RS_OFF + 128;
static constexpr size_t ARENA_BYTES = S_OFF + (size_t)CH_ * T_ * SP_ * 4; // ~570 MB

__device__ __align__(256) unsigned char g_arena[ARENA_BYTES];

template <typename Tp>
__device__ __forceinline__ Tp* ap(size_t off) { return (Tp*)(g_arena + off); }

// ---------------- dtype detect
__global__ void detect_kernel(const unsigned* __restrict__ w)
{
    if (threadIdx.x == 0)
        *ap<int>(FLAG_OFF) = (w[0] == 0x3F803F80u) ? 1 : 0;
}

// ---------------- single merged convert
struct SrcPtrs { const void* p[12]; };
static constexpr size_t SEGB[13] = {
    0,
    NX,
    NX + NCLS,
    NX + NCLS + NLN1,
    NX + NCLS + 2 * NLN1,
    NX + NCLS + 2 * NLN1 + NWP,
    NX + NCLS + 2 * NLN1 + 2 * NWP,
    NX + NCLS + 2 * NLN1 + 3 * NWP,
    NX + NCLS + 2 * NLN1 + 4 * NWP,
    NX + NCLS + 2 * NLN1 + 4 * NWP + NLN2,
    NX + NCLS + 2 * NLN1 + 4 * NWP + 2 * NLN2,
    NX + NCLS + 2 * NLN1 + 4 * NWP + 2 * NLN2 + NW1,
    NX + NCLS + 2 * NLN1 + 4 * NWP + 2 * NLN2 + 2 * NW1,
};
static constexpr size_t NTOT_CVT = SEGB[12];

__global__ __launch_bounds__(256) void cvt_all_kernel(SrcPtrs sp)
{
    size_t i = (size_t)blockIdx.x * 256 + threadIdx.x;
    if (i >= NTOT_CVT) return;
    int seg = 0;
#pragma unroll
    for (int k = 1; k < 12; k++) seg += (i >= SEGB[k]);
    size_t li = i - SEGB[seg];
    const void* src = sp.p[seg];
    float v = (*ap<int>(FLAG_OFF))
        ? __bfloat162float(((const bf16*)src)[li])
        : ((const float*)src)[li];
    ap<float>(XF_OFF)[i] = v;
}

__device__ __forceinline__ float xin_val(int b, int t, int c)
{
    return (t == 0) ? ap<float>(CLSF_OFF)[b * C_ + c]
                    : ap<float>(XF_OFF)[((size_t)b * HW_ + (t - 1)) * C_ + c];
}

// ---------------- LN1 stats A/B, apply
__global__ __launch_bounds__(256) void stats1a_kernel()
{
    const int TC = T_ * C_;
    const int SL = (TC + 15) / 16;
    int b = blockIdx.x, s = blockIdx.y, tid = threadIdx.x;
    int e0 = s * SL, e1 = min(e0 + SL, TC);
    __shared__ double r1[256], r2[256];
    double sm = 0.0, s2 = 0.0;
    for (int e = e0 + tid; e < e1; e += 256) {
        int t = e / C_, c = e - t * C_;
        double v = (double)xin_val(b, t, c);
        sm += v; s2 += v * v;
    }
    r1[tid] = sm; r2[tid] = s2; __syncthreads();
    for (int o = 128; o; o >>= 1) {
        if (tid < o) { r1[tid] += r1[tid + o]; r2[tid] += r2[tid + o]; }
        __syncthreads();
    }
    if (tid == 0) {
        double2* ps = ap<double2>(PS_OFF);
        ps[b * 16 + s] = make_double2(r1[0], r2[0]);
    }
}

__global__ __launch_bounds__(64) void stats1b_kernel()
{
    int b = blockIdx.x, lane = threadIdx.x;
    const double2* ps = ap<double2>(PS_OFF);
    double sm = 0.0, s2 = 0.0;
    if (lane < 16) { sm = ps[b * 16 + lane].x; s2 = ps[b * 16 + lane].y; }
    for (int o = 8; o; o >>= 1) { sm += __shfl_down(sm, o); s2 += __shfl_down(s2, o); }
    if (lane == 0) {
        const int TC = T_ * C_;
        double m = sm / TC;
        double var = s2 / TC - m * m;
        ap<float>(MU_OFF)[b] = (float)m;
        ap<float>(RS_OFF)[b] = (float)(1.0 / sqrt(var + 1e-5));
    }
}

__global__ __launch_bounds__(256) void ln1_apply_kernel()
{
    size_t i = (size_t)blockIdx.x * 256 + threadIdx.x;
    if (i >= NRES) return;
    int b = (int)(i / (T_ * C_));
    int rem = (int)(i - (size_t)b * T_ * C_);
    int t = rem / C_, c = rem - t * C_;
    float v = xin_val(b, t, c);
    ap<float>(X1_OFF)[i] = (v - ap<float>(MU_OFF)[b]) * ap<float>(RS_OFF)[b]
                           * ap<float>(LN1W_OFF)[t * C_ + c]
                           + ap<float>(LN1B_OFF)[t * C_ + c];
}

// ---------------- 128x128 fp32 GEMM: C[m][n] = sum_k A[m][k]*Bf[n][k]
// 256 thr, 8x8 microtile, float4 global loads, transposed-k LDS.
// EMODE 0: store fp32; 2: gelu; 3: +X2N -> split out; 4: XM + RES=acc+x_in
template<int EMODE>
__global__ __launch_bounds__(256) void gemm128(
    size_t a_off, size_t b_off, float* __restrict__ dout, size_t c_off,
    int M, int N, int K)
{
    __shared__ float As2[16][136];
    __shared__ float Bs2[16][136];
    int bm = blockIdx.x * 128, bn = blockIdx.y * 128;
    int tid = threadIdx.x;
    int tr = tid >> 4, tc = tid & 15;
    const float* A  = ap<float>(a_off);
    const float* Bf = ap<float>(b_off);
    float acc[8][8] = {};
    for (int k0 = 0; k0 < K; k0 += 16) {
#pragma unroll
        for (int j = 0; j < 2; j++) {
            int id = tid * 2 + j;
            int row = id >> 2, kc = (id & 3) * 4;
            int gm = bm + row;
            float4 v = (gm < M) ? *(const float4*)&A[(size_t)gm * K + k0 + kc]
                                : make_float4(0.f, 0.f, 0.f, 0.f);
            As2[kc + 0][row] = v.x; As2[kc + 1][row] = v.y;
            As2[kc + 2][row] = v.z; As2[kc + 3][row] = v.w;
            int gn = bn + row;
            float4 w = (gn < N) ? *(const float4*)&Bf[(size_t)gn * K + k0 + kc]
                                : make_float4(0.f, 0.f, 0.f, 0.f);
            Bs2[kc + 0][row] = w.x; Bs2[kc + 1][row] = w.y;
            Bs2[kc + 2][row] = w.z; Bs2[kc + 3][row] = w.w;
        }
        __syncthreads();
#pragma unroll
        for (int kk = 0; kk < 16; kk++) {
            float a0[8], b0[8];
            *(float4*)&a0[0] = *(const float4*)&As2[kk][tr * 8];
            *(float4*)&a0[4] = *(const float4*)&As2[kk][tr * 8 + 4];
            *(float4*)&b0[0] = *(const float4*)&Bs2[kk][tc * 8];
            *(float4*)&b0[4] = *(const float4*)&Bs2[kk][tc * 8 + 4];
#pragma unroll
            for (int i = 0; i < 8; i++)
#pragma unroll
                for (int j = 0; j < 8; j++) acc[i][j] += a0[i] * b0[j];
        }
        __syncthreads();
    }
#pragma unroll
    for (int i = 0; i < 8; i++) {
        int gm = bm + tr * 8 + i;
        if (gm >= M) continue;
#pragma unroll
        for (int j = 0; j < 8; j++) {
            int gn = bn + tc * 8 + j;
            if (gn >= N) continue;
            float v = acc[i][j];
            size_t idx = (size_t)gm * N + gn;
            if (EMODE == 0) {
                ap<float>(c_off)[idx] = v;
            } else if (EMODE == 2) {
                v = 0.5f * v * (1.f + erff(v * 0.70710678f));
                ap<float>(c_off)[idx] = v;
            } else if (EMODE == 4) {
                ap<float>(c_off)[idx] = v;
                int b = gm / T_, t = gm - b * T_;
                ap<float>(RES_OFF)[idx] = v + xin_val(b, t, gn);
            } else {
                v += ap<float>(X2N_OFF)[idx];
                int b = gm / TP_, t = gm - b * TP_;
                size_t off = (t == 0)
                    ? ((size_t)B_ * (TP_ - 1) * C_ + (size_t)b * C_ + gn)
                    : ((size_t)(b * (TP_ - 1) + (t - 1)) * C_ + gn);
                dout[off] = v;
            }
        }
    }
}

// ---------------- attention step 1: S = scale * Q K^T (128x128, batched)
__global__ __launch_bounds__(256) void gemm_s128(int bh0)
{
    __shared__ float As2[16][136];
    __shared__ float Bs2[16][136];
    const float* Q  = ap<float>(Q_OFF);
    const float* Kf = ap<float>(K_OFF);
    float* S        = ap<float>(S_OFF);
    int lbh = blockIdx.z;
    int bh = bh0 + lbh;
    int b = bh >> 3, h = bh & 7;
    size_t qkb = (size_t)b * T_ * C_ + (size_t)h * D_;
    int m0 = blockIdx.x * 128, n0 = blockIdx.y * 128;
    int tid = threadIdx.x;
    int tr = tid >> 4, tc = tid & 15;
    float acc[8][8] = {};
    for (int k0 = 0; k0 < D_; k0 += 16) {
#pragma unroll
        for (int j = 0; j < 2; j++) {
            int id = tid * 2 + j;
            int row = id >> 2, kc = (id & 3) * 4;
            int gm = m0 + row, gn = n0 + row;
            float4 v = (gm < T_) ? *(const float4*)&Q[qkb + (size_t)gm * C_ + k0 + kc]
                                 : make_float4(0.f, 0.f, 0.f, 0.f);
            As2[kc + 0][row] = v.x; As2[kc + 1][row] = v.y;
            As2[kc + 2][row] = v.z; As2[kc + 3][row] = v.w;
            float4 w = (gn < T_) ? *(const float4*)&Kf[qkb + (size_t)gn * C_ + k0 + kc]
                                 : make_float4(0.f, 0.f, 0.f, 0.f);
            Bs2[kc + 0][row] = w.x; Bs2[kc + 1][row] = w.y;
            Bs2[kc + 2][row] = w.z; Bs2[kc + 3][row] = w.w;
        }
        __syncthreads();
#pragma unroll
        for (int kk = 0; kk < 16; kk++) {
            float a0[8], b0[8];
            *(float4*)&a0[0] = *(const float4*)&As2[kk][tr * 8];
            *(float4*)&a0[4] = *(const float4*)&As2[kk][tr * 8 + 4];
            *(float4*)&b0[0] = *(const float4*)&Bs2[kk][tc * 8];
            *(float4*)&b0[4] = *(const float4*)&Bs2[kk][tc * 8 + 4];
#pragma unroll
            for (int i = 0; i < 8; i++)
#pragma unroll
                for (int j = 0; j < 8; j++) acc[i][j] += a0[i] * b0[j];
        }
        __syncthreads();
    }
    const float scale = 0.14433756729740643f;
#pragma unroll
    for (int i = 0; i < 8; i++) {
        int m = m0 + tr * 8 + i;
        if (m >= T_) continue;
#pragma unroll
        for (int j = 0; j < 8; j++) {
            int n = n0 + tc * 8 + j;
            if (n < T_) S[((size_t)lbh * T_ + m) * SP_ + n] = acc[i][j] * scale;
        }
    }
}

// ---------------- attention step 2: row softmax (stride SP_)
__global__ __launch_bounds__(256) void softmax_kernel()
{
    float* S = ap<float>(S_OFF);
    int wave = threadIdx.x >> 6, lane = threadIdx.x & 63;
    size_t row = (size_t)blockIdx.x * 4 + wave;
    float* p = S + row * SP_;
    float v[13];
    float m = -1e30f;
#pragma unroll
    for (int j = 0; j < 13; j++) {
        int idx = lane + 64 * j;
        v[j] = (idx < T_) ? p[idx] : -1e30f;
        m = fmaxf(m, v[j]);
    }
    for (int o = 32; o; o >>= 1) m = fmaxf(m, __shfl_down(m, o));
    m = __shfl(m, 0);
    float s = 0.f;
#pragma unroll
    for (int j = 0; j < 13; j++) { v[j] = expf(v[j] - m); s += v[j]; }
    for (int o = 32; o; o >>= 1) s += __shfl_down(s, o);
    s = __shfl(s, 0);
    float inv = 1.f / s;
#pragma unroll
    for (int j = 0; j < 13; j++) {
        int idx = lane + 64 * j;
        if (idx < T_) p[idx] = v[j] * inv;
    }
}

// ---------------- attention step 3: O = P V (128x48, 8x3 microtile)
__global__ __launch_bounds__(256) void gemm_pv128(int bh0)
{
    __shared__ float As2[16][136];
    __shared__ float Bs[16][52];
    const float* S  = ap<float>(S_OFF);
    const float* Vf = ap<float>(V_OFF);
    float* A        = ap<float>(ATT_OFF);
    int lbh = blockIdx.y;
    int bh = bh0 + lbh;
    int b = bh >> 3, h = bh & 7;
    size_t vbase = (size_t)b * T_ * C_ + (size_t)h * D_;
    int m0 = blockIdx.x * 128;
    int tid = threadIdx.x;
    int tr = tid >> 4, tc = tid & 15;
    float acc[8][3] = {};
    for (int k0 = 0; k0 < T_; k0 += 16) {
#pragma unroll
        for (int j = 0; j < 2; j++) {
            int id = tid * 2 + j;
            int row = id >> 2, kc = (id & 3) * 4;
            int gm = m0 + row;
            // S rows padded to SP_ (mult of 4) -> aligned float4; cols k0+kc..+3
            float4 v;
            if (gm < T_ && k0 + kc + 3 < T_)
                v = *(const float4*)&S[((size_t)lbh * T_ + gm) * SP_ + k0 + kc];
            else {
                float x0 = (gm < T_ && k0 + kc + 0 < T_) ? S[((size_t)lbh * T_ + gm) * SP_ + k0 + kc + 0] : 0.f;
                float x1 = (gm < T_ && k0 + kc + 1 < T_) ? S[((size_t)lbh * T_ + gm) * SP_ + k0 + kc + 1] : 0.f;
                float x2 = (gm < T_ && k0 + kc + 2 < T_) ? S[((size_t)lbh * T_ + gm) * SP_ + k0 + kc + 2] : 0.f;
                float x3 = (gm < T_ && k0 + kc + 3 < T_) ? S[((size_t)lbh * T_ + gm) * SP_ + k0 + kc + 3] : 0.f;
                v = make_float4(x0, x1, x2, x3);
            }
            As2[kc + 0][row] = v.x; As2[kc + 1][row] = v.y;
            As2[kc + 2][row] = v.z; As2[kc + 3][row] = v.w;
        }
        for (int e = tid; e < 768; e += 256) {
            int kk = e / 48, n = e - kk * 48;
            int gk = k0 + kk;
            Bs[kk][n] = (gk < T_) ? Vf[vbase + (size_t)gk * C_ + n] : 0.f;
        }
        __syncthreads();
#pragma unroll
        for (int kk = 0; kk < 16; kk++) {
            float a0[8];
            *(float4*)&a0[0] = *(const float4*)&As2[kk][tr * 8];
            *(float4*)&a0[4] = *(const float4*)&As2[kk][tr * 8 + 4];
            float b0 = Bs[kk][tc * 3], b1 = Bs[kk][tc * 3 + 1], b2 = Bs[kk][tc * 3 + 2];
#pragma unroll
            for (int i = 0; i < 8; i++) {
                acc[i][0] += a0[i] * b0;
                acc[i][1] += a0[i] * b1;
                acc[i][2] += a0[i] * b2;
            }
        }
        __syncthreads();
    }
#pragma unroll
    for (int i = 0; i < 8; i++) {
        int m = m0 + tr * 8 + i;
        if (m >= T_) continue;
#pragma unroll
        for (int j = 0; j < 3; j++)
            A[vbase + (size_t)m * C_ + tc * 3 + j] = acc[i][j];
    }
}

// ---------------- ci stage A/B (double)
__global__ __launch_bounds__(384) void cia_kernel()
{
    int b = blockIdx.x, s = blockIdx.y, c = threadIdx.x;
    const float* xm = ap<float>(XM_OFF);
    const int SL = (T_ + 7) / 8;
    int t0 = s * SL, t1 = min(t0 + SL, T_);
    double sm = 0.0;
    for (int t = t0; t < t1; t++) sm += (double)xm[((size_t)b * T_ + t) * C_ + c];
    ap<double>(CIP_OFF)[((size_t)b * 8 + s) * C_ + c] = sm;
}

__global__ __launch_bounds__(384) void cib_kernel()
{
    int b = blockIdx.x, c = threadIdx.x;
    const double* pp = ap<double>(CIP_OFF);
    double sm = 0.0;
#pragma unroll
    for (int s = 0; s < 8; s++) sm += pp[((size_t)b * 8 + s) * C_ + c];
    sm /= (double)T_;
    ap<double>(CID_OFF)[b * C_ + c] = 1.0 / (1.0 + exp(-sm));
}

// ---------------- ca (double)
__global__ __launch_bounds__(64) void ca_kernel()
{
    const float* xres1 = ap<float>(RES_OFF);
    const double* ci   = ap<double>(CID_OFF);
    int idx = blockIdx.x;
    int b = idx / HW_, n = idx - b * HW_;
    int lane = threadIdx.x;
    double s = 0.0;
    for (int c = lane; c < C_; c += 64)
        s += (double)xres1[((size_t)b * T_ + 1 + n) * C_ + c] * ci[b * C_ + c];
    for (int o = 32; o; o >>= 1) s += __shfl_down(s, o);
    if (lane == 0) ap<double>(CAD_OFF)[idx] = s;
}

// ---------------- stable rank
__global__ __launch_bounds__(256) void rank_kernel()
{
    const double* ca = ap<double>(CAD_OFF);
    int* perm = ap<int>(PERM_OFF);
    int b = blockIdx.x, tid = threadIdx.x;
    __shared__ double cs[HW_];
    for (int i = tid; i < HW_; i += 256) cs[i] = ca[b * HW_ + i];
    __syncthreads();
    for (int i = tid; i < HW_; i += 256) {
        double vi = cs[i];
        int r = 0;
        for (int j = 0; j < HW_; j++) {
            double vj = cs[j];
            r += (vj < vi) || (vj == vi && j < i);
        }
        if (r >= HW_ - TP_ + 1) perm[b * (TP_ - 1) + (r - (HW_ - TP_ + 1))] = i;
    }
}

// ---------------- LN2 A/B/apply
__global__ __launch_bounds__(256) void ln2a_kernel()
{
    const float* xres1 = ap<float>(RES_OFF);
    const int* perm = ap<int>(PERM_OFF);
    const int TC = TP_ * C_;
    const int SL = (TC + 7) / 8;
    int b = blockIdx.x, s = blockIdx.y, tid = threadIdx.x;
    int e0 = s * SL, e1 = min(e0 + SL, TC);
    __shared__ double r1[256], r2[256];
    double sm = 0.0, s2 = 0.0;
    for (int e = e0 + tid; e < e1; e += 256) {
        int t = e / C_, c = e - t * C_;
        int st = (t == 0) ? 0 : 1 + perm[b * (TP_ - 1) + t - 1];
        double v = (double)xres1[((size_t)b * T_ + st) * C_ + c];
        sm += v; s2 += v * v;
    }
    r1[tid] = sm; r2[tid] = s2; __syncthreads();
    for (int o = 128; o; o >>= 1) {
        if (tid < o) { r1[tid] += r1[tid + o]; r2[tid] += r2[tid + o]; }
        __syncthreads();
    }
    if (tid == 0) {
        double2* ps = ap<double2>(L2PS_OFF);
        ps[b * 8 + s] = make_double2(r1[0], r2[0]);
    }
}

__global__ __launch_bounds__(64) void ln2b_kernel()
{
    int b = blockIdx.x, lane = threadIdx.x;
    const double2* ps = ap<double2>(L2PS_OFF);
    double sm = 0.0, s2 = 0.0;
    if (lane < 8) { sm = ps[b * 8 + lane].x; s2 = ps[b * 8 + lane].y; }
    for (int o = 4; o; o >>= 1) { sm += __shfl_down(sm, o); s2 += __shfl_down(s2, o); }
    if (lane == 0) {
        const int TC = TP_ * C_;
        double m = sm / TC;
        double var = s2 / TC - m * m;
        ap<float>(L2MU_OFF)[b] = (float)m;
        ap<float>(L2RS_OFF)[b] = (float)(1.0 / sqrt(var + 1e-5));
    }
}

__global__ __launch_bounds__(256) void ln2_apply_kernel()
{
    size_t i = (size_t)blockIdx.x * 256 + threadIdx.x;
    if (i >= NX2) return;
    const int TC = TP_ * C_;
    int b = (int)(i / TC);
    int e = (int)(i - (size_t)b * TC);
    int t = e / C_, c = e - t * C_;
    const int* perm = ap<int>(PERM_OFF);
    int st = (t == 0) ? 0 : 1 + perm[b * (TP_ - 1) + t - 1];
    float v = ap<float>(RES_OFF)[((size_t)b * T_ + st) * C_ + c];
    ap<float>(X2N_OFF)[i] = (v - ap<float>(L2MU_OFF)[b]) * ap<float>(L2RS_OFF)[b]
                            * ap<float>(LN2W_OFF)[e] + ap<float>(LN2B_OFF)[e];
}

extern "C" void kernel_launch(void* const* d_in, const int* in_sizes, int n_in,
                              void* d_out, int out_size, void* d_ws, size_t ws_size,
                              hipStream_t stream)
{
    float* out = (float*)d_out;
    (void)d_ws; (void)ws_size; (void)in_sizes; (void)n_in; (void)out_size;

    const int M1 = B_ * T_;            // 25120
    const int M2 = B_ * TP_;           // 6304
    const int GM1 = (M1 + 127) / 128;  // 197
    const int GM2 = (M2 + 127) / 128;  // 50
    const int GT  = (T_ + 127) / 128;  // 7

    // 0. dtype detect + merged conversion
    detect_kernel<<<1, 64, 0, stream>>>((const unsigned*)d_in[2]);
    SrcPtrs sp;
    for (int i = 0; i < 12; i++) sp.p[i] = d_in[i];
    cvt_all_kernel<<<(int)((NTOT_CVT + 255) / 256), 256, 0, stream>>>(sp);

    // 1. LN1
    stats1a_kernel<<<dim3(B_, 16), 256, 0, stream>>>();
    stats1b_kernel<<<B_, 64, 0, stream>>>();
    ln1_apply_kernel<<<(int)((NRES + 255) / 256), 256, 0, stream>>>();

    // 2. QKV projections (128-tile GEMM)
    gemm128<0><<<dim3(GM1, C_ / 128), 256, 0, stream>>>(X1_OFF, WQF_OFF, nullptr, Q_OFF, M1, C_, C_);
    gemm128<0><<<dim3(GM1, C_ / 128), 256, 0, stream>>>(X1_OFF, WKF_OFF, nullptr, K_OFF, M1, C_, C_);
    gemm128<0><<<dim3(GM1, C_ / 128), 256, 0, stream>>>(X1_OFF, WVF_OFF, nullptr, V_OFF, M1, C_, C_);

    // 3. attention
    for (int bh0 = 0; bh0 < B_ * H_; bh0 += CH_) {
        gemm_s128<<<dim3(GT, GT, CH_), 256, 0, stream>>>(bh0);
        softmax_kernel<<<CH_ * T_ / 4 + (CH_ * T_ % 4 ? 1 : 0), 256, 0, stream>>>();
        gemm_pv128<<<dim3(GT, CH_), 256, 0, stream>>>(bh0);
    }
    gemm128<4><<<dim3(GM1, C_ / 128), 256, 0, stream>>>(ATT_OFF, WOF_OFF, nullptr, XM_OFF, M1, C_, C_);

    // 4. ci, ca, rank, LN2
    cia_kernel<<<dim3(B_, 8), 384, 0, stream>>>();
    cib_kernel<<<B_, 384, 0, stream>>>();
    ca_kernel<<<B_ * HW_, 64, 0, stream>>>();
    rank_kernel<<<B_, 256, 0, stream>>>();
    ln2a_kernel<<<dim3(B_, 8), 256, 0, stream>>>();
    ln2b_kernel<<<B_, 64, 0, stream>>>();
    ln2_apply_kernel<<<(int)((NX2 + 255) / 256), 256, 0, stream>>>();

    // 5. FFN
    gemm128<2><<<dim3(GM2, FF_ / 128), 256, 0, stream>>>(X2N_OFF, W1F_OFF, nullptr, H_OFF, M2, FF_, C_);
    gemm128<3><<<dim3(GM2, C_ / 128), 256, 0, stream>>>(H_OFF, W2F_OFF, out, 0, M2, C_, FF_);
}

// Round 13
// 2274.034 us; speedup vs baseline: 1.1892x; 1.1892x over previous
//
#include <hip/hip_runtime.h>
#include <hip/hip_bf16.h>
#include <math.h>

typedef __hip_bfloat16 bf16;

#define B_ 32
#define HW_ 784
#define T_ 785
#define TP_ 197
#define C_ 384
#define H_ 8
#define D_ 48
#define FF_ 1536
#define CH_ 64    // (b,h) pairs per attention chunk
#define SP_ 788   // padded S row stride (floats)

// ---------------- sizes (elements) ----------------
static constexpr size_t NRES = (size_t)B_ * T_ * C_;
static constexpr size_t NX   = (size_t)B_ * HW_ * C_;
static constexpr size_t NCLS = (size_t)B_ * C_;
static constexpr size_t NLN1 = (size_t)T_ * C_;
static constexpr size_t NWP  = (size_t)C_ * C_;
static constexpr size_t NLN2 = (size_t)TP_ * C_;
static constexpr size_t NW1  = (size_t)FF_ * C_;
static constexpr size_t NX2  = (size_t)B_ * TP_ * C_;
static constexpr size_t NH   = (size_t)B_ * TP_ * FF_;

// ---------------- arena byte offsets ----------------
static constexpr size_t XF_OFF   = 0;
static constexpr size_t CLSF_OFF = XF_OFF   + NX   * 4;
static constexpr size_t LN1W_OFF = CLSF_OFF + NCLS * 4;
static constexpr size_t LN1B_OFF = LN1W_OFF + NLN1 * 4;
static constexpr size_t WQF_OFF  = LN1B_OFF + NLN1 * 4;   // Wq,Wk,Wv contiguous!
static constexpr size_t WKF_OFF  = WQF_OFF  + NWP  * 4;
static constexpr size_t WVF_OFF  = WKF_OFF  + NWP  * 4;
static constexpr size_t WOF_OFF  = WVF_OFF  + NWP  * 4;
static constexpr size_t LN2W_OFF = WOF_OFF  + NWP  * 4;
static constexpr size_t LN2B_OFF = LN2W_OFF + NLN2 * 4;
static constexpr size_t W1F_OFF  = LN2B_OFF + NLN2 * 4;
static constexpr size_t W2F_OFF  = W1F_OFF  + NW1  * 4;
static constexpr size_t X1_OFF   = W2F_OFF  + NW1  * 4;
static constexpr size_t Q_OFF    = X1_OFF   + NRES * 4;   // Q,K,V contiguous!
static constexpr size_t K_OFF    = Q_OFF    + NRES * 4;
static constexpr size_t V_OFF    = K_OFF    + NRES * 4;
static constexpr size_t ATT_OFF  = V_OFF    + NRES * 4;
static constexpr size_t XM_OFF   = ATT_OFF  + NRES * 4;
static constexpr size_t RES_OFF  = XM_OFF   + NRES * 4;
static constexpr size_t X2N_OFF  = RES_OFF  + NRES * 4;
static constexpr size_t H_OFF    = X2N_OFF  + NX2  * 4;
static constexpr size_t MU_OFF   = H_OFF    + NH   * 4;
static constexpr size_t RS_OFF   = MU_OFF   + 128;
static constexpr size_t CID_OFF  = RS_OFF   + 128;
static constexpr size_t CAD_OFF  = CID_OFF  + NCLS * 8;
static constexpr size_t PERM_OFF = CAD_OFF  + (size_t)B_ * HW_ * 8;
static constexpr size_t FLAG_OFF = PERM_OFF + (size_t)B_ * (TP_ - 1) * 4;
static constexpr size_t PS_OFF   = FLAG_OFF + 16;
static constexpr size_t CIP_OFF  = PS_OFF + 32 * 16 * 16;
static constexpr size_t L2PS_OFF = CIP_OFF + (size_t)B_ * 8 * C_ * 8;
static constexpr size_t L2MU_OFF = L2PS_OFF + 32 * 8 * 16;
static constexpr size_t L2RS_OFF = L2MU_OFF + 128;
static constexpr size_t S_OFF    = L2RS_OFF + 128;
static constexpr size_t PART_OFF = S_OFF;   // FFN2 split-K partials ALIAS dead S region
static constexpr size_t ARENA_BYTES = S_OFF + (size_t)CH_ * T_ * SP_ * 4; // ~570 MB

__device__ __align__(256) unsigned char g_arena[ARENA_BYTES];

template <typename Tp>
__device__ __forceinline__ Tp* ap(size_t off) { return (Tp*)(g_arena + off); }

// ---------------- dtype detect
__global__ void detect_kernel(const unsigned* __restrict__ w)
{
    if (threadIdx.x == 0)
        *ap<int>(FLAG_OFF) = (w[0] == 0x3F803F80u) ? 1 : 0;
}

// ---------------- single merged convert
struct SrcPtrs { const void* p[12]; };
static constexpr size_t SEGB[13] = {
    0,
    NX,
    NX + NCLS,
    NX + NCLS + NLN1,
    NX + NCLS + 2 * NLN1,
    NX + NCLS + 2 * NLN1 + NWP,
    NX + NCLS + 2 * NLN1 + 2 * NWP,
    NX + NCLS + 2 * NLN1 + 3 * NWP,
    NX + NCLS + 2 * NLN1 + 4 * NWP,
    NX + NCLS + 2 * NLN1 + 4 * NWP + NLN2,
    NX + NCLS + 2 * NLN1 + 4 * NWP + 2 * NLN2,
    NX + NCLS + 2 * NLN1 + 4 * NWP + 2 * NLN2 + NW1,
    NX + NCLS + 2 * NLN1 + 4 * NWP + 2 * NLN2 + 2 * NW1,
};
static constexpr size_t NTOT_CVT = SEGB[12];

__global__ __launch_bounds__(256) void cvt_all_kernel(SrcPtrs sp)
{
    size_t i = (size_t)blockIdx.x * 256 + threadIdx.x;
    if (i >= NTOT_CVT) return;
    int seg = 0;
#pragma unroll
    for (int k = 1; k < 12; k++) seg += (i >= SEGB[k]);
    size_t li = i - SEGB[seg];
    const void* src = sp.p[seg];
    float v = (*ap<int>(FLAG_OFF))
        ? __bfloat162float(((const bf16*)src)[li])
        : ((const float*)src)[li];
    ap<float>(XF_OFF)[i] = v;
}

__device__ __forceinline__ float xin_val(int b, int t, int c)
{
    return (t == 0) ? ap<float>(CLSF_OFF)[b * C_ + c]
                    : ap<float>(XF_OFF)[((size_t)b * HW_ + (t - 1)) * C_ + c];
}

__device__ __forceinline__ float4 xin_val4(int b, int t, int c)
{
    const float* src = (t == 0)
        ? ap<float>(CLSF_OFF) + (size_t)b * C_ + c
        : ap<float>(XF_OFF) + ((size_t)b * HW_ + (t - 1)) * C_ + c;
    return *(const float4*)src;
}

// ---------------- LN1 stats A/B, apply
__global__ __launch_bounds__(256) void stats1a_kernel()
{
    const int TC = T_ * C_;
    const int SL = (TC + 15) / 16;
    int b = blockIdx.x, s = blockIdx.y, tid = threadIdx.x;
    int e0 = s * SL, e1 = min(e0 + SL, TC);
    __shared__ double r1[256], r2[256];
    double sm = 0.0, s2 = 0.0;
    for (int e = e0 + tid; e < e1; e += 256) {
        int t = e / C_, c = e - t * C_;
        double v = (double)xin_val(b, t, c);
        sm += v; s2 += v * v;
    }
    r1[tid] = sm; r2[tid] = s2; __syncthreads();
    for (int o = 128; o; o >>= 1) {
        if (tid < o) { r1[tid] += r1[tid + o]; r2[tid] += r2[tid + o]; }
        __syncthreads();
    }
    if (tid == 0) {
        double2* ps = ap<double2>(PS_OFF);
        ps[b * 16 + s] = make_double2(r1[0], r2[0]);
    }
}

__global__ __launch_bounds__(64) void stats1b_kernel()
{
    int b = blockIdx.x, lane = threadIdx.x;
    const double2* ps = ap<double2>(PS_OFF);
    double sm = 0.0, s2 = 0.0;
    if (lane < 16) { sm = ps[b * 16 + lane].x; s2 = ps[b * 16 + lane].y; }
    for (int o = 8; o; o >>= 1) { sm += __shfl_down(sm, o); s2 += __shfl_down(s2, o); }
    if (lane == 0) {
        const int TC = T_ * C_;
        double m = sm / TC;
        double var = s2 / TC - m * m;
        ap<float>(MU_OFF)[b] = (float)m;
        ap<float>(RS_OFF)[b] = (float)(1.0 / sqrt(var + 1e-5));
    }
}

__global__ __launch_bounds__(256) void ln1_apply_kernel()
{
    size_t i = (size_t)blockIdx.x * 256 + threadIdx.x;
    if (i >= NRES) return;
    int b = (int)(i / (T_ * C_));
    int rem = (int)(i - (size_t)b * T_ * C_);
    int t = rem / C_, c = rem - t * C_;
    float v = xin_val(b, t, c);
    ap<float>(X1_OFF)[i] = (v - ap<float>(MU_OFF)[b]) * ap<float>(RS_OFF)[b]
                           * ap<float>(LN1W_OFF)[t * C_ + c]
                           + ap<float>(LN1B_OFF)[t * C_ + c];
}

// ---------------- 128x128 fp32 GEMM, conflict-free 4+4 fragments, no spill.
// EMODE 0: store fp32 @ c_off; 2: gelu @ c_off;
// EMODE 4: XM @ c_off AND RES = acc + x_in; 5: QKV routing (N=1152 -> Q/K/V)
template<int EMODE>
__global__ __launch_bounds__(256, 2) void gemm128(
    size_t a_off, size_t b_off, size_t c_off, int M, int N, int K)
{
    __shared__ float As2[16][136];
    __shared__ float Bs2[16][136];
    int bm = blockIdx.x * 128, bn = blockIdx.y * 128;
    int tid = threadIdx.x;
    int tr = tid >> 4, tc = tid & 15;
    const float* A  = ap<float>(a_off);
    const float* Bf = ap<float>(b_off);
    float acc[8][8] = {};
    for (int k0 = 0; k0 < K; k0 += 16) {
#pragma unroll
        for (int j = 0; j < 2; j++) {
            int id = tid * 2 + j;
            int row = id >> 2, kc = (id & 3) * 4;
            int gm = bm + row;
            float4 v = (gm < M) ? *(const float4*)&A[(size_t)gm * K + k0 + kc]
                                : make_float4(0.f, 0.f, 0.f, 0.f);
            As2[kc + 0][row] = v.x; As2[kc + 1][row] = v.y;
            As2[kc + 2][row] = v.z; As2[kc + 3][row] = v.w;
            int gn = bn + row;   // N is always a multiple of 128 here
            float4 w = *(const float4*)&Bf[(size_t)gn * K + k0 + kc];
            Bs2[kc + 0][row] = w.x; Bs2[kc + 1][row] = w.y;
            Bs2[kc + 2][row] = w.z; Bs2[kc + 3][row] = w.w;
        }
        __syncthreads();
#pragma unroll
        for (int kk = 0; kk < 16; kk++) {
            float a0[8], b0[8];
            *(float4*)&a0[0] = *(const float4*)&As2[kk][tr * 4];
            *(float4*)&a0[4] = *(const float4*)&As2[kk][64 + tr * 4];
            *(float4*)&b0[0] = *(const float4*)&Bs2[kk][tc * 4];
            *(float4*)&b0[4] = *(const float4*)&Bs2[kk][64 + tc * 4];
#pragma unroll
            for (int i = 0; i < 8; i++)
#pragma unroll
                for (int j = 0; j < 8; j++) acc[i][j] += a0[i] * b0[j];
        }
        __syncthreads();
    }
#pragma unroll
    for (int i = 0; i < 8; i++) {
        int gm = bm + ((i < 4) ? tr * 4 + i : 64 + tr * 4 + i - 4);
        if (gm >= M) continue;
#pragma unroll
        for (int jg = 0; jg < 2; jg++) {
            int cb = bn + jg * 64 + tc * 4;
            float4 v = make_float4(acc[i][jg * 4 + 0], acc[i][jg * 4 + 1],
                                   acc[i][jg * 4 + 2], acc[i][jg * 4 + 3]);
            if (EMODE == 0) {
                *(float4*)&ap<float>(c_off)[(size_t)gm * N + cb] = v;
            } else if (EMODE == 2) {
                v.x = 0.5f * v.x * (1.f + erff(v.x * 0.70710678f));
                v.y = 0.5f * v.y * (1.f + erff(v.y * 0.70710678f));
                v.z = 0.5f * v.z * (1.f + erff(v.z * 0.70710678f));
                v.w = 0.5f * v.w * (1.f + erff(v.w * 0.70710678f));
                *(float4*)&ap<float>(c_off)[(size_t)gm * N + cb] = v;
            } else if (EMODE == 4) {
                *(float4*)&ap<float>(c_off)[(size_t)gm * N + cb] = v;
                int b = gm / T_, t = gm - b * T_;
                float4 xi = xin_val4(b, t, cb);
                float4 r = make_float4(v.x + xi.x, v.y + xi.y, v.z + xi.z, v.w + xi.w);
                *(float4*)&ap<float>(RES_OFF)[(size_t)gm * N + cb] = r;
            } else {   // EMODE 5: QKV routing (cols 0..383 -> Q, .. -> K, V)
                int seg = bn / C_;
                int cn = cb - seg * C_;
                float* dst = ap<float>(Q_OFF) + (size_t)seg * NRES;
                *(float4*)&dst[(size_t)gm * C_ + cn] = v;
            }
        }
    }
}

// ---------------- FFN2 split-K: partials into PART (aliases dead S region)
__global__ __launch_bounds__(256, 2) void gemm128_sk(
    size_t a_off, size_t b_off, int M, int N, int K)
{
    __shared__ float As2[16][136];
    __shared__ float Bs2[16][136];
    int bm = blockIdx.x * 128, bn = blockIdx.y * 128;
    int sidx = blockIdx.z;
    int kbeg = sidx * (K / 4), kend = kbeg + K / 4;
    int tid = threadIdx.x;
    int tr = tid >> 4, tc = tid & 15;
    const float* A  = ap<float>(a_off);
    const float* Bf = ap<float>(b_off);
    float acc[8][8] = {};
    for (int k0 = kbeg; k0 < kend; k0 += 16) {
#pragma unroll
        for (int j = 0; j < 2; j++) {
            int id = tid * 2 + j;
            int row = id >> 2, kc = (id & 3) * 4;
            int gm = bm + row;
            float4 v = (gm < M) ? *(const float4*)&A[(size_t)gm * K + k0 + kc]
                                : make_float4(0.f, 0.f, 0.f, 0.f);
            As2[kc + 0][row] = v.x; As2[kc + 1][row] = v.y;
            As2[kc + 2][row] = v.z; As2[kc + 3][row] = v.w;
            int gn = bn + row;
            float4 w = *(const float4*)&Bf[(size_t)gn * K + k0 + kc];
            Bs2[kc + 0][row] = w.x; Bs2[kc + 1][row] = w.y;
            Bs2[kc + 2][row] = w.z; Bs2[kc + 3][row] = w.w;
        }
        __syncthreads();
#pragma unroll
        for (int kk = 0; kk < 16; kk++) {
            float a0[8], b0[8];
            *(float4*)&a0[0] = *(const float4*)&As2[kk][tr * 4];
            *(float4*)&a0[4] = *(const float4*)&As2[kk][64 + tr * 4];
            *(float4*)&b0[0] = *(const float4*)&Bs2[kk][tc * 4];
            *(float4*)&b0[4] = *(const float4*)&Bs2[kk][64 + tc * 4];
#pragma unroll
            for (int i = 0; i < 8; i++)
#pragma unroll
                for (int j = 0; j < 8; j++) acc[i][j] += a0[i] * b0[j];
        }
        __syncthreads();
    }
    float* part = ap<float>(PART_OFF) + (size_t)sidx * M * N;
#pragma unroll
    for (int i = 0; i < 8; i++) {
        int gm = bm + ((i < 4) ? tr * 4 + i : 64 + tr * 4 + i - 4);
        if (gm >= M) continue;
#pragma unroll
        for (int jg = 0; jg < 2; jg++) {
            int cb = bn + jg * 64 + tc * 4;
            float4 v = make_float4(acc[i][jg * 4 + 0], acc[i][jg * 4 + 1],
                                   acc[i][jg * 4 + 2], acc[i][jg * 4 + 3]);
            *(float4*)&part[(size_t)gm * N + cb] = v;
        }
    }
}

// ---------------- FFN2 reduce: sum partials + x2n resid -> split store to out
__global__ __launch_bounds__(256) void ffn2_reduce_kernel(float* __restrict__ out)
{
    const size_t tot = (size_t)B_ * TP_ * C_;
    size_t i = (size_t)blockIdx.x * 256 + threadIdx.x;
    if (i >= tot) return;
    const float* part = ap<float>(PART_OFF);
    float v = part[i] + part[tot + i] + part[2 * tot + i] + part[3 * tot + i]
            + ap<float>(X2N_OFF)[i];
    int gm = (int)(i / C_);
    int gn = (int)(i - (size_t)gm * C_);
    int b = gm / TP_, t = gm - b * TP_;
    size_t off = (t == 0)
        ? ((size_t)B_ * (TP_ - 1) * C_ + (size_t)b * C_ + gn)
        : ((size_t)(b * (TP_ - 1) + (t - 1)) * C_ + gn);
    out[off] = v;
}

// ---------------- attention step 1: S = scale * Q K^T
__global__ __launch_bounds__(256, 2) void gemm_s128(int bh0)
{
    __shared__ float As2[16][136];
    __shared__ float Bs2[16][136];
    const float* Q  = ap<float>(Q_OFF);
    const float* Kf = ap<float>(K_OFF);
    float* S        = ap<float>(S_OFF);
    int lbh = blockIdx.z;
    int bh = bh0 + lbh;
    int b = bh >> 3, h = bh & 7;
    size_t qkb = (size_t)b * T_ * C_ + (size_t)h * D_;
    int m0 = blockIdx.x * 128, n0 = blockIdx.y * 128;
    int tid = threadIdx.x;
    int tr = tid >> 4, tc = tid & 15;
    float acc[8][8] = {};
    for (int k0 = 0; k0 < D_; k0 += 16) {
#pragma unroll
        for (int j = 0; j < 2; j++) {
            int id = tid * 2 + j;
            int row = id >> 2, kc = (id & 3) * 4;
            int gm = m0 + row, gn = n0 + row;
            float4 v = (gm < T_) ? *(const float4*)&Q[qkb + (size_t)gm * C_ + k0 + kc]
                                 : make_float4(0.f, 0.f, 0.f, 0.f);
            As2[kc + 0][row] = v.x; As2[kc + 1][row] = v.y;
            As2[kc + 2][row] = v.z; As2[kc + 3][row] = v.w;
            float4 w = (gn < T_) ? *(const float4*)&Kf[qkb + (size_t)gn * C_ + k0 + kc]
                                 : make_float4(0.f, 0.f, 0.f, 0.f);
            Bs2[kc + 0][row] = w.x; Bs2[kc + 1][row] = w.y;
            Bs2[kc + 2][row] = w.z; Bs2[kc + 3][row] = w.w;
        }
        __syncthreads();
#pragma unroll
        for (int kk = 0; kk < 16; kk++) {
            float a0[8], b0[8];
            *(float4*)&a0[0] = *(const float4*)&As2[kk][tr * 4];
            *(float4*)&a0[4] = *(const float4*)&As2[kk][64 + tr * 4];
            *(float4*)&b0[0] = *(const float4*)&Bs2[kk][tc * 4];
            *(float4*)&b0[4] = *(const float4*)&Bs2[kk][64 + tc * 4];
#pragma unroll
            for (int i = 0; i < 8; i++)
#pragma unroll
                for (int j = 0; j < 8; j++) acc[i][j] += a0[i] * b0[j];
        }
        __syncthreads();
    }
    const float scale = 0.14433756729740643f;
#pragma unroll
    for (int i = 0; i < 8; i++) {
        int m = m0 + ((i < 4) ? tr * 4 + i : 64 + tr * 4 + i - 4);
        if (m >= T_) continue;
        float* srow = S + ((size_t)lbh * T_ + m) * SP_;
#pragma unroll
        for (int jg = 0; jg < 2; jg++) {
            int nb = n0 + jg * 64 + tc * 4;
            if (nb + 3 < T_) {
                float4 v = make_float4(acc[i][jg * 4 + 0] * scale, acc[i][jg * 4 + 1] * scale,
                                       acc[i][jg * 4 + 2] * scale, acc[i][jg * 4 + 3] * scale);
                *(float4*)&srow[nb] = v;
            } else {
#pragma unroll
                for (int j = 0; j < 4; j++)
                    if (nb + j < T_) srow[nb + j] = acc[i][jg * 4 + j] * scale;
            }
        }
    }
}

// ---------------- attention step 2: row softmax
__global__ __launch_bounds__(256) void softmax_kernel()
{
    float* S = ap<float>(S_OFF);
    int wave = threadIdx.x >> 6, lane = threadIdx.x & 63;
    size_t row = (size_t)blockIdx.x * 4 + wave;
    float* p = S + row * SP_;
    float v[13];
    float m = -1e30f;
#pragma unroll
    for (int j = 0; j < 13; j++) {
        int idx = lane + 64 * j;
        v[j] = (idx < T_) ? p[idx] : -1e30f;
        m = fmaxf(m, v[j]);
    }
    for (int o = 32; o; o >>= 1) m = fmaxf(m, __shfl_down(m, o));
    m = __shfl(m, 0);
    float s = 0.f;
#pragma unroll
    for (int j = 0; j < 13; j++) { v[j] = expf(v[j] - m); s += v[j]; }
    for (int o = 32; o; o >>= 1) s += __shfl_down(s, o);
    s = __shfl(s, 0);
    float inv = 1.f / s;
#pragma unroll
    for (int j = 0; j < 13; j++) {
        int idx = lane + 64 * j;
        if (idx < T_) p[idx] = v[j] * inv;
    }
}

// ---------------- attention step 3: O = P V (128x48, 8x3)
__global__ __launch_bounds__(256, 2) void gemm_pv128(int bh0)
{
    __shared__ float As2[16][136];
    __shared__ float Bs[16][52];
    const float* S  = ap<float>(S_OFF);
    const float* Vf = ap<float>(V_OFF);
    float* A        = ap<float>(ATT_OFF);
    int lbh = blockIdx.y;
    int bh = bh0 + lbh;
    int b = bh >> 3, h = bh & 7;
    size_t vbase = (size_t)b * T_ * C_ + (size_t)h * D_;
    int m0 = blockIdx.x * 128;
    int tid = threadIdx.x;
    int tr = tid >> 4, tc = tid & 15;
    float acc[8][3] = {};
    for (int k0 = 0; k0 < T_; k0 += 16) {
#pragma unroll
        for (int j = 0; j < 2; j++) {
            int id = tid * 2 + j;
            int row = id >> 2, kc = (id & 3) * 4;
            int gm = m0 + row;
            float4 v;
            if (gm < T_ && k0 + kc + 3 < T_)
                v = *(const float4*)&S[((size_t)lbh * T_ + gm) * SP_ + k0 + kc];
            else {
                float x0 = (gm < T_ && k0 + kc + 0 < T_) ? S[((size_t)lbh * T_ + gm) * SP_ + k0 + kc + 0] : 0.f;
                float x1 = (gm < T_ && k0 + kc + 1 < T_) ? S[((size_t)lbh * T_ + gm) * SP_ + k0 + kc + 1] : 0.f;
                float x2 = (gm < T_ && k0 + kc + 2 < T_) ? S[((size_t)lbh * T_ + gm) * SP_ + k0 + kc + 2] : 0.f;
                float x3 = (gm < T_ && k0 + kc + 3 < T_) ? S[((size_t)lbh * T_ + gm) * SP_ + k0 + kc + 3] : 0.f;
                v = make_float4(x0, x1, x2, x3);
            }
            As2[kc + 0][row] = v.x; As2[kc + 1][row] = v.y;
            As2[kc + 2][row] = v.z; As2[kc + 3][row] = v.w;
        }
        for (int e = tid; e < 768; e += 256) {
            int kk = e / 48, n = e - kk * 48;
            int gk = k0 + kk;
            Bs[kk][n] = (gk < T_) ? Vf[vbase + (size_t)gk * C_ + n] : 0.f;
        }
        __syncthreads();
#pragma unroll
        for (int kk = 0; kk < 16; kk++) {
            float a0[8];
            *(float4*)&a0[0] = *(const float4*)&As2[kk][tr * 4];
            *(float4*)&a0[4] = *(const float4*)&As2[kk][64 + tr * 4];
            float b0 = Bs[kk][tc * 3], b1 = Bs[kk][tc * 3 + 1], b2 = Bs[kk][tc * 3 + 2];
#pragma unroll
            for (int i = 0; i < 8; i++) {
                acc[i][0] += a0[i] * b0;
                acc[i][1] += a0[i] * b1;
                acc[i][2] += a0[i] * b2;
            }
        }
        __syncthreads();
    }
#pragma unroll
    for (int i = 0; i < 8; i++) {
        int m = m0 + ((i < 4) ? tr * 4 + i : 64 + tr * 4 + i - 4);
        if (m >= T_) continue;
#pragma unroll
        for (int j = 0; j < 3; j++)
            A[vbase + (size_t)m * C_ + tc * 3 + j] = acc[i][j];
    }
}

// ---------------- ci stage A/B (double)
__global__ __launch_bounds__(384) void cia_kernel()
{
    int b = blockIdx.x, s = blockIdx.y, c = threadIdx.x;
    const float* xm = ap<float>(XM_OFF);
    const int SL = (T_ + 7) / 8;
    int t0 = s * SL, t1 = min(t0 + SL, T_);
    double sm = 0.0;
    for (int t = t0; t < t1; t++) sm += (double)xm[((size_t)b * T_ + t) * C_ + c];
    ap<double>(CIP_OFF)[((size_t)b * 8 + s) * C_ + c] = sm;
}

__global__ __launch_bounds__(384) void cib_kernel()
{
    int b = blockIdx.x, c = threadIdx.x;
    const double* pp = ap<double>(CIP_OFF);
    double sm = 0.0;
#pragma unroll
    for (int s = 0; s < 8; s++) sm += pp[((size_t)b * 8 + s) * C_ + c];
    sm /= (double)T_;
    ap<double>(CID_OFF)[b * C_ + c] = 1.0 / (1.0 + exp(-sm));
}

// ---------------- ca (double)
__global__ __launch_bounds__(64) void ca_kernel()
{
    const float* xres1 = ap<float>(RES_OFF);
    const double* ci   = ap<double>(CID_OFF);
    int idx = blockIdx.x;
    int b = idx / HW_, n = idx - b * HW_;
    int lane = threadIdx.x;
    double s = 0.0;
    for (int c = lane; c < C_; c += 64)
        s += (double)xres1[((size_t)b * T_ + 1 + n) * C_ + c] * ci[b * C_ + c];
    for (int o = 32; o; o >>= 1) s += __shfl_down(s, o);
    if (lane == 0) ap<double>(CAD_OFF)[idx] = s;
}

// ---------------- stable rank
__global__ __launch_bounds__(256) void rank_kernel()
{
    const double* ca = ap<double>(CAD_OFF);
    int* perm = ap<int>(PERM_OFF);
    int b = blockIdx.x, tid = threadIdx.x;
    __shared__ double cs[HW_];
    for (int i = tid; i < HW_; i += 256) cs[i] = ca[b * HW_ + i];
    __syncthreads();
    for (int i = tid; i < HW_; i += 256) {
        double vi = cs[i];
        int r = 0;
        for (int j = 0; j < HW_; j++) {
            double vj = cs[j];
            r += (vj < vi) || (vj == vi && j < i);
        }
        if (r >= HW_ - TP_ + 1) perm[b * (TP_ - 1) + (r - (HW_ - TP_ + 1))] = i;
    }
}

// ---------------- LN2 A/B/apply
__global__ __launch_bounds__(256) void ln2a_kernel()
{
    const float* xres1 = ap<float>(RES_OFF);
    const int* perm = ap<int>(PERM_OFF);
    const int TC = TP_ * C_;
    const int SL = (TC + 7) / 8;
    int b = blockIdx.x, s = blockIdx.y, tid = threadIdx.x;
    int e0 = s * SL, e1 = min(e0 + SL, TC);
    __shared__ double r1[256], r2[256];
    double sm = 0.0, s2 = 0.0;
    for (int e = e0 + tid; e < e1; e += 256) {
        int t = e / C_, c = e - t * C_;
        int st = (t == 0) ? 0 : 1 + perm[b * (TP_ - 1) + t - 1];
        double v = (double)xres1[((size_t)b * T_ + st) * C_ + c];
        sm += v; s2 += v * v;
    }
    r1[tid] = sm; r2[tid] = s2; __syncthreads();
    for (int o = 128; o; o >>= 1) {
        if (tid < o) { r1[tid] += r1[tid + o]; r2[tid] += r2[tid + o]; }
        __syncthreads();
    }
    if (tid == 0) {
        double2* ps = ap<double2>(L2PS_OFF);
        ps[b * 8 + s] = make_double2(r1[0], r2[0]);
    }
}

__global__ __launch_bounds__(64) void ln2b_kernel()
{
    int b = blockIdx.x, lane = threadIdx.x;
    const double2* ps = ap<double2>(L2PS_OFF);
    double sm = 0.0, s2 = 0.0;
    if (lane < 8) { sm = ps[b * 8 + lane].x; s2 = ps[b * 8 + lane].y; }
    for (int o = 4; o; o >>= 1) { sm += __shfl_down(sm, o); s2 += __shfl_down(s2, o); }
    if (lane == 0) {
        const int TC = TP_ * C_;
        double m = sm / TC;
        double var = s2 / TC - m * m;
        ap<float>(L2MU_OFF)[b] = (float)m;
        ap<float>(L2RS_OFF)[b] = (float)(1.0 / sqrt(var + 1e-5));
    }
}

__global__ __launch_bounds__(256) void ln2_apply_kernel()
{
    size_t i = (size_t)blockIdx.x * 256 + threadIdx.x;
    if (i >= NX2) return;
    const int TC = TP_ * C_;
    int b = (int)(i / TC);
    int e = (int)(i - (size_t)b * TC);
    int t = e / C_, c = e - t * C_;
    const int* perm = ap<int>(PERM_OFF);
    int st = (t == 0) ? 0 : 1 + perm[b * (TP_ - 1) + t - 1];
    float v = ap<float>(RES_OFF)[((size_t)b * T_ + st) * C_ + c];
    ap<float>(X2N_OFF)[i] = (v - ap<float>(L2MU_OFF)[b]) * ap<float>(L2RS_OFF)[b]
                            * ap<float>(LN2W_OFF)[e] + ap<float>(LN2B_OFF)[e];
}

extern "C" void kernel_launch(void* const* d_in, const int* in_sizes, int n_in,
                              void* d_out, int out_size, void* d_ws, size_t ws_size,
                              hipStream_t stream)
{
    float* out = (float*)d_out;
    (void)d_ws; (void)ws_size; (void)in_sizes; (void)n_in; (void)out_size;

    const int M1 = B_ * T_;            // 25120
    const int M2 = B_ * TP_;           // 6304
    const int GM1 = (M1 + 127) / 128;  // 197
    const int GM2 = (M2 + 127) / 128;  // 50
    const int GT  = (T_ + 127) / 128;  // 7

    // 0. dtype detect + merged conversion
    detect_kernel<<<1, 64, 0, stream>>>((const unsigned*)d_in[2]);
    SrcPtrs sp;
    for (int i = 0; i < 12; i++) sp.p[i] = d_in[i];
    cvt_all_kernel<<<(int)((NTOT_CVT + 255) / 256), 256, 0, stream>>>(sp);

    // 1. LN1
    stats1a_kernel<<<dim3(B_, 16), 256, 0, stream>>>();
    stats1b_kernel<<<B_, 64, 0, stream>>>();
    ln1_apply_kernel<<<(int)((NRES + 255) / 256), 256, 0, stream>>>();

    // 2. merged QKV projection: one GEMM, N = 3*C = 1152, routed epilogue
    gemm128<5><<<dim3(GM1, (3 * C_) / 128), 256, 0, stream>>>(
        X1_OFF, WQF_OFF, 0, M1, 3 * C_, C_);

    // 3. attention
    for (int bh0 = 0; bh0 < B_ * H_; bh0 += CH_) {
        gemm_s128<<<dim3(GT, GT, CH_), 256, 0, stream>>>(bh0);
        softmax_kernel<<<CH_ * T_ / 4 + (CH_ * T_ % 4 ? 1 : 0), 256, 0, stream>>>();
        gemm_pv128<<<dim3(GT, CH_), 256, 0, stream>>>(bh0);
    }
    // Wo projection fused with residual
    gemm128<4><<<dim3(GM1, C_ / 128), 256, 0, stream>>>(ATT_OFF, WOF_OFF, XM_OFF, M1, C_, C_);

    // 4. ci, ca, rank, LN2
    cia_kernel<<<dim3(B_, 8), 384, 0, stream>>>();
    cib_kernel<<<B_, 384, 0, stream>>>();
    ca_kernel<<<B_ * HW_, 64, 0, stream>>>();
    rank_kernel<<<B_, 256, 0, stream>>>();
    ln2a_kernel<<<dim3(B_, 8), 256, 0, stream>>>();
    ln2b_kernel<<<B_, 64, 0, stream>>>();
    ln2_apply_kernel<<<(int)((NX2 + 255) / 256), 256, 0, stream>>>();

    // 5. FFN: gelu GEMM, then split-K=4 GEMM + reduce (residual + split store)
    gemm128<2><<<dim3(GM2, FF_ / 128), 256, 0, stream>>>(X2N_OFF, W1F_OFF, H_OFF, M2, FF_, C_);
    gemm128_sk<<<dim3(GM2, C_ / 128, 4), 256, 0, stream>>>(H_OFF, W2F_OFF, M2, C_, FF_);
    ffn2_reduce_kernel<<<(int)((NX2 + 255) / 256), 256, 0, stream>>>(out);
}